// Round 9
// baseline (34.345 us; speedup 1.0000x reference)
//
#include <hip/hip_runtime.h>

// Path signature, depth 4, D=8. Output layout (matches JAX flatten):
//   s1[8] | s2[64] (i*8+j) | s3[512] (i*64+j*8+k) | s4[4096] (i*512+j*64+k*8+l)
//
// TWO kernels (each inter-kernel dependency boundary costs ~10-11us in L2
// writeback/invalidate + completion sync; 3-kernel floor was ~28us):
//   k1: 256 blocks, each computes the signature of its ~32-increment chunk
//       (state fully thread-private in registers, barrier-free scan);
//       partials written with nontemporal stores (read-once downstream,
//       less dirty L2 at the boundary).
//   k2: 16 blocks; each folds its 16 chunk sigs (Chen product, LDS-staged B).
//       Blocks 1..15 nt-store group results + release a flag; block 0 keeps
//       its group product in registers, polls the 15 flags, acquire-fences
//       once, restages, folds the 15 results, stores d_out. This replaces the
//       second kernel boundary (+k3) with a cheap 16->1 in-kernel handoff.
#define SIGLEN 4680
#define S1OFF 0
#define S2OFF 8
#define S3OFF 72
#define S4OFF 584
#define NCHUNK 256
#define NG 16
#define MAGIC 0x13572468u
#define MAXLEN 128
#define LROW 592  // LDS floats per staged sig (584 + 8 pad)

typedef float f4v __attribute__((ext_vector_type(4)));
typedef float f2v __attribute__((ext_vector_type(2)));

struct SigRegs { float s4[16]; float a1, a2, a30, a31; };

// s3 chunk swizzle: float4 chunk c (0..127) lives at float-offset
// S3OFF + 4*(c ^ ((c>>4)&7)). Involution, bijective, 16B-aligned. Makes the
// 16*(t&31)-pattern b128 reads 4-way instead of 16-way conflicted.
__device__ __forceinline__ int s3off(int c) {
  return S3OFF + 4 * (c ^ ((c >> 4) & 7));
}

__device__ __forceinline__ void load_sig(SigRegs& A, const float* __restrict__ B,
                                         int i_idx, int t) {
  const float4* p4 = (const float4*)(B + S4OFF + 16 * t);
#pragma unroll
  for (int r = 0; r < 4; ++r) {
    const float4 v = p4[r];
    A.s4[4 * r] = v.x; A.s4[4 * r + 1] = v.y; A.s4[4 * r + 2] = v.z; A.s4[4 * r + 3] = v.w;
  }
  A.a1 = B[S1OFF + i_idx];
  A.a2 = B[S2OFF + (t >> 2)];
  const float2 a3i = *(const float2*)(B + S3OFF + 2 * t);
  A.a30 = a3i.x; A.a31 = a3i.y;
}

__device__ __forceinline__ void store_sig(const SigRegs& A, float* __restrict__ o,
                                          int i_idx, int t) {
  if ((t & 31) == 0) o[S1OFF + i_idx] = A.a1;
  if ((t & 3) == 0) o[S2OFF + (t >> 2)] = A.a2;
  *(float2*)(o + S3OFF + 2 * t) = make_float2(A.a30, A.a31);
  float4* o4 = (float4*)(o + S4OFF + 16 * t);
#pragma unroll
  for (int r = 0; r < 4; ++r)
    o4[r] = make_float4(A.s4[4 * r], A.s4[4 * r + 1], A.s4[4 * r + 2], A.s4[4 * r + 3]);
}

// Nontemporal variant: results are read exactly once by the next stage.
__device__ __forceinline__ void store_sig_nt(const SigRegs& A, float* __restrict__ o,
                                             int i_idx, int t) {
  if ((t & 31) == 0) __builtin_nontemporal_store(A.a1, o + S1OFF + i_idx);
  if ((t & 3) == 0) __builtin_nontemporal_store(A.a2, o + S2OFF + (t >> 2));
  f2v v2; v2.x = A.a30; v2.y = A.a31;
  __builtin_nontemporal_store(v2, (f2v*)(o + S3OFF + 2 * t));
  f4v* o4 = (f4v*)(o + S4OFF + 16 * t);
#pragma unroll
  for (int r = 0; r < 4; ++r) {
    f4v v; v.x = A.s4[4 * r]; v.y = A.s4[4 * r + 1];
    v.z = A.s4[4 * r + 2]; v.w = A.s4[4 * r + 3];
    __builtin_nontemporal_store(v, o4 + r);
  }
}

__device__ __forceinline__ void wait_flag_relaxed(unsigned* f) {
  for (long i = 0; i < 200000000L; ++i) {
    if (__hip_atomic_load(f, __ATOMIC_RELAXED, __HIP_MEMORY_SCOPE_AGENT) == MAGIC)
      return;
  }
}

// Chen left-fold A <- A*B; B lower levels from LDS row R, B.s4 own-slice from
// registers q4. Math identical to the verified round-2 kernel:
//   c4 = a4 + b4 + a1(x)b3 + a2(x)b2 + a3(x)b1
//   c3 = a3 + b3 + a1(x)b2 + a2(x)b1 ; c2 = a2 + b2 + a1(x)b1 ; c1 = a1 + b1
__device__ __forceinline__ void fold_lds(SigRegs& A, const float* __restrict__ R,
                                         const float4* __restrict__ q4,
                                         int i_idx, int j_idx, int k0, int t) {
  const float4 b1lo = *(const float4*)(R + S1OFF);
  const float4 b1hi = *(const float4*)(R + S1OFF + 4);
  const float b1i = R[S1OFF + i_idx];
  const float b1j = R[S1OFF + j_idx];
  const float2 b1k = *(const float2*)(R + S1OFF + k0);
  const float b2own = R[S2OFF + (t >> 2)];
  const float2 b2p = *(const float2*)(R + S2OFF + ((2 * t) & 63));
  const float2 b3p = *(const float2*)(R + s3off(t >> 1) + 2 * (t & 1));
  const float4* q2 = (const float4*)(R + S2OFF + 16 * (t & 3));
#pragma unroll
  for (int r = 0; r < 4; ++r) {
    const float4 v2 = q2[r];
    const float4 v3 = *(const float4*)(R + s3off(4 * (t & 31) + r));
    const float4 v4 = q4[r];
    const float a3v = (r < 2) ? A.a30 : A.a31;   // e<8 -> a30
    const float4 bb = (r & 1) ? b1hi : b1lo;     // b1v[(4r+c)&7]
    A.s4[4 * r + 0] += v4.x + A.a1 * v3.x + A.a2 * v2.x + a3v * bb.x;
    A.s4[4 * r + 1] += v4.y + A.a1 * v3.y + A.a2 * v2.y + a3v * bb.y;
    A.s4[4 * r + 2] += v4.z + A.a1 * v3.z + A.a2 * v2.z + a3v * bb.z;
    A.s4[4 * r + 3] += v4.w + A.a1 * v3.w + A.a2 * v2.w + a3v * bb.w;
  }
  A.a30 += b3p.x + A.a1 * b2p.x + A.a2 * b1k.x;
  A.a31 += b3p.y + A.a1 * b2p.y + A.a2 * b1k.y;
  A.a2 += b2own + A.a1 * b1j;
  A.a1 += b1i;
}

__device__ __forceinline__ void loadq4(float4* dst, const float* __restrict__ gbase,
                                       int m, int t) {
  const float4* g = (const float4*)(gbase + (long)m * SIGLEN + S4OFF + 16 * t);
#pragma unroll
  for (int r = 0; r < 4; ++r) dst[r] = g[r];
}

// Stage lower levels (146 float4 chunks x nsig sigs) into LDS rows [0, nsig).
// Static 10-slot batch (issue all loads, then all LDS writes); s3 swizzled.
__device__ __forceinline__ void stage_sigs(const float* __restrict__ gbase, int nsig,
                                           float* __restrict__ lsig, int t) {
  const int lim = nsig * 146;
  float4 vals[10];
#pragma unroll
  for (int s = 0; s < 10; ++s) {
    const int v = t + 256 * s;
    const int vc = (v < lim) ? v : (lim - 1);
    const int sig = vc / 146;
    const int r = vc - sig * 146;
    vals[s] = *(const float4*)(gbase + (long)sig * SIGLEN + 4 * r);
  }
#pragma unroll
  for (int s = 0; s < 10; ++s) {
    const int v = t + 256 * s;
    if (v < lim) {
      const int sig = v / 146;
      const int r = v - sig * 146;
      const int off = (r < 18) ? 4 * r : s3off(r - 18);
      *(float4*)(lsig + sig * LROW + off) = vals[s];
    }
  }
}

// Fold 15 sigs into A: LDS rows [r0, r0+15), q4 slices from gbase sigs
// [s0, s0+15). 2-deep double-buffer, runtime loop (live-set control; deeper
// rings / full unroll spilled to scratch in rounds 4-5).
__device__ __forceinline__ void fold_seq15(SigRegs& A, const float* __restrict__ gbase,
                                           int s0, const float* __restrict__ lsig,
                                           int r0, int i_idx, int j_idx, int k0, int t) {
  float4 qA[4], qB[4];
  loadq4(qA, gbase, s0, t);
  loadq4(qB, gbase, s0 + 1, t);
#pragma unroll 1
  for (int m = 0; m + 2 < 15; m += 2) {  // m = 0,2,...,12 (14 folds)
    fold_lds(A, lsig + (r0 + m) * LROW, qA, i_idx, j_idx, k0, t);
    loadq4(qA, gbase, s0 + m + 2, t);
    fold_lds(A, lsig + (r0 + m + 1) * LROW, qB, i_idx, j_idx, k0, t);
    if (m + 3 < 15) loadq4(qB, gbase, s0 + m + 3, t);
  }
  fold_lds(A, lsig + (r0 + 14) * LROW, qA, i_idx, j_idx, k0, t);  // fold 15
}

// ------------------------- kernel 1: chunk signatures -------------------------
__global__ __launch_bounds__(256, 1) void sig_chunk(const float* __restrict__ path,
                                                    float* __restrict__ partials,
                                                    int nInc) {
  __shared__ float4 pl[(MAXLEN + 1) * 2];
  __shared__ float4 dv[MAXLEN * 2];
  const int t = threadIdx.x;
  const int c = blockIdx.x;
  const int i_idx = t >> 5;
  const int j_idx = (t >> 2) & 7;
  const int k0 = 2 * (t & 3);

  const long start = ((long)c * nInc) / NCHUNK;
  const long end = ((long)(c + 1) * nInc) / NCHUNK;
  const int len = (int)(end - start);

  const float4* gp = (const float4*)(path + start * 8);
  for (int idx = t; idx < (len + 1) * 2; idx += 256) pl[idx] = gp[idx];
  __syncthreads();
  for (int idx = t; idx < len * 2; idx += 256) {
    float4 a = pl[idx + 2], b = pl[idx];
    dv[idx] = make_float4(a.x - b.x, a.y - b.y, a.z - b.z, a.w - b.w);
  }
  __syncthreads();
  const float* dvf = (const float*)dv;

  SigRegs A;
#pragma unroll
  for (int e = 0; e < 16; ++e) A.s4[e] = 0.f;
  A.a1 = 0.f; A.a2 = 0.f; A.a30 = 0.f; A.a31 = 0.f;

  for (int it = 0; it < len; ++it) {
    const float4 d0 = dv[it * 2], d1 = dv[it * 2 + 1];
    const float dxl[8] = {d0.x, d0.y, d0.z, d0.w, d1.x, d1.y, d1.z, d1.w};
    const float dxi = dvf[it * 8 + i_idx];
    const float dxj = dvf[it * 8 + j_idx];
    const float2 dkk = *(const float2*)(dvf + it * 8 + k0);

    const float inner = 0.5f * A.a2 + dxj * ((1.f / 6.f) * A.a1 + (1.f / 24.f) * dxi);
    const float c0 = A.a30 + dkk.x * inner;
    const float c1 = A.a31 + dkk.y * inner;
#pragma unroll
    for (int l = 0; l < 8; ++l) A.s4[l] += c0 * dxl[l];
#pragma unroll
    for (int l = 0; l < 8; ++l) A.s4[8 + l] += c1 * dxl[l];
    const float common3 = A.a2 + dxj * (0.5f * A.a1 + (1.f / 6.f) * dxi);
    A.a30 += common3 * dkk.x;
    A.a31 += common3 * dkk.y;
    A.a2 += dxj * (A.a1 + 0.5f * dxi);
    A.a1 += dxi;
  }

  store_sig_nt(A, partials + (long)c * SIGLEN, i_idx, t);
}

// ---------------- kernel 2: group folds + in-kernel 16->1 handoff ----------------
__global__ __launch_bounds__(256, 1) void sig_fold(const float* __restrict__ partials,
                                                   float* __restrict__ out,
                                                   float* __restrict__ g2,
                                                   unsigned* __restrict__ cflag) {
  __shared__ float lsig[NG * LROW];  // 37888 B
  const int t = threadIdx.x;
  const int b = blockIdx.x;
  const int i_idx = t >> 5;
  const int j_idx = (t >> 2) & 7;
  const int k0 = 2 * (t & 3);

  // ---- phase 1: fold this block's 16 chunk sigs ----
  const float* gbase = partials + (long)(NG * b) * SIGLEN;
  stage_sigs(gbase, NG, lsig, t);  // rows 0..15 (row 0 unused by folds)
  SigRegs A;
  load_sig(A, gbase, i_idx, t);    // A = sig 0 of the group
  __syncthreads();                 // LDS staging complete
  fold_seq15(A, gbase, 1, lsig, 1, i_idx, j_idx, k0, t);  // fold sigs 1..15

  if (b != 0) {
    store_sig_nt(A, g2 + (long)b * SIGLEN, i_idx, t);
    __syncthreads();  // all of this block's result stores issued/drained
    if (t == 0) {
      __threadfence();  // release: result visible at agent scope
      __hip_atomic_store(&cflag[b], MAGIC, __ATOMIC_RELAXED, __HIP_MEMORY_SCOPE_AGENT);
    }
    return;
  }

  // ---- phase 2 (block 0 only): fold the 15 other group results ----
  if (t < NG - 1) wait_flag_relaxed(&cflag[t + 1]);
  __syncthreads();  // all flags seen; also: all lsig reads of phase 1 done
  __builtin_amdgcn_fence(__ATOMIC_ACQUIRE, "agent");  // one invalidate, not per poll

  stage_sigs(g2 + SIGLEN, NG - 1, lsig, t);  // g2[1..15] -> rows 0..14
  __syncthreads();
  fold_seq15(A, g2 + SIGLEN, 0, lsig, 0, i_idx, j_idx, k0, t);

  store_sig(A, out, i_idx, t);

  // reset flags for the next graph replay (replays are stream-serialized;
  // kernel-end writeback publishes these)
  __syncthreads();
  if (t < NG - 1) cflag[t + 1] = 0u;
}

extern "C" void kernel_launch(void* const* d_in, const int* in_sizes, int n_in,
                              void* d_out, int out_size, void* d_ws, size_t ws_size,
                              hipStream_t stream) {
  const float* path = (const float*)d_in[0];
  float* out = (float*)d_out;
  const int L = in_sizes[0] / 8;
  const int nInc = L - 1;

  float* partials = (float*)d_ws;                    // NCHUNK * SIGLEN floats
  float* g2 = partials + (long)NCHUNK * SIGLEN;      // NG * SIGLEN floats
  unsigned* cflag = (unsigned*)(g2 + (long)NG * SIGLEN);  // NG uints

  sig_chunk<<<NCHUNK, 256, 0, stream>>>(path, partials, nInc);
  sig_fold<<<NG, 256, 0, stream>>>(partials, out, g2, cflag);
}